// Round 4
// baseline (350.641 us; speedup 1.0000x reference)
//
#include <hip/hip_runtime.h>

#define DIM 1024
#define SEQ 2048

typedef __attribute__((ext_vector_type(8))) short bf16x8;
typedef __attribute__((ext_vector_type(4))) float f32x4;
typedef __attribute__((ext_vector_type(4))) unsigned short us4;
typedef __attribute__((ext_vector_type(4))) _Float16 h4;

__device__ __forceinline__ unsigned short f2bf(float f) {
    union { float f; unsigned int u; } v; v.f = f;
    unsigned int r = (v.u + 0x7FFFu + ((v.u >> 16) & 1u)) >> 16;
    return (unsigned short)r;
}

#define GLOAD(gp, lp) __builtin_amdgcn_global_load_lds( \
    (const __attribute__((address_space(1))) unsigned int*)(gp), \
    (__attribute__((address_space(3))) unsigned int*)(lp), 16, 0, 0)

__global__ __launch_bounds__(256) void cast_f32_bf16(const float* __restrict__ src,
                                                     unsigned short* __restrict__ dst, int n) {
    int i = (blockIdx.x * 256 + threadIdx.x) * 8;
    if (i >= n) return;
    float4 a = *(const float4*)(src + i);
    float4 b = *(const float4*)(src + i + 4);
    us4 lo = { f2bf(a.x), f2bf(a.y), f2bf(a.z), f2bf(a.w) };
    us4 hi = { f2bf(b.x), f2bf(b.y), f2bf(b.z), f2bf(b.w) };
    *(us4*)(dst + i) = lo;
    *(us4*)(dst + i + 4) = hi;
}

// ---------------------------------------------------------------------------
// 256x256 GEMM core, single-barrier phases: C += A[256,K] * B[256,K]^T.
// 512 threads = 8 waves (2M x 4N), per-wave 128x64 output. BK=32, 4 LDS bufs
// (32 KiB each = 128 KiB). Per phase j: counted vmcnt -> barrier -> 12x
// ds_read_b128 (buf j, XOR-swizzled) || 4x global_load_lds (buf j+3) ->
// setprio(1) -> 32 MFMA -> setprio(0).  Never vmcnt(0) mid-loop.
// ---------------------------------------------------------------------------
#define STAGE4(sb, kt) do { \
    GLOAD(A + (size_t)(lr) * lda + (kt) + csrc,       smem + (sb) * 32768 + wid * 1024); \
    GLOAD(A + (size_t)(128 + lr) * lda + (kt) + csrc, smem + (sb) * 32768 + 8192 + wid * 1024); \
    GLOAD(B + (size_t)(lr) * ldb + (kt) + csrc,       smem + (sb) * 32768 + 16384 + wid * 1024); \
    GLOAD(B + (size_t)(128 + lr) * ldb + (kt) + csrc, smem + (sb) * 32768 + 24576 + wid * 1024); \
} while (0)

__device__ __forceinline__ void gemm256_core(
    const unsigned short* __restrict__ A, const unsigned short* __restrict__ B,
    int lda, int ldb, int K, char* smem, f32x4 acc[8][4])
{
    const int tid = threadIdx.x;
    const int lane = tid & 63;
    const int wid = tid >> 6;
    const int wm = wid >> 2;                 // 0..1
    const int wn = wid & 3;                  // 0..3
    const int lr = tid >> 2;                 // staging row 0..127 (per q-half)
    const int csrc = ((tid & 3) ^ ((tid >> 3) & 3)) * 8;   // pre-swizzled src chunk

    // Fragment LDS offsets (buf-relative). cr key depends only on lane.
    int aoff[8], boff[4];
    {
        int arow = wm * 128 + (lane & 15);
        int cr = (lane >> 4) ^ ((arow >> 1) & 3);
#pragma unroll
        for (int mi = 0; mi < 8; mi++) aoff[mi] = (arow + mi * 16) * 64 + cr * 16;
        int brow = wn * 64 + (lane & 15);
        int crb = (lane >> 4) ^ ((brow >> 1) & 3);
#pragma unroll
        for (int nj = 0; nj < 4; nj++) boff[nj] = 16384 + (brow + nj * 16) * 64 + crb * 16;
    }

    const int nph = K >> 5;                  // phases of K=32

    // prologue: stage bufs 0,1,2
#pragma unroll
    for (int jb = 0; jb < 3; jb++) STAGE4(jb, jb * 32);

    for (int j = 0; j < nph; ++j) {
        if (j + 2 < nph)      asm volatile("s_waitcnt vmcnt(8)" ::: "memory");
        else if (j + 1 < nph) asm volatile("s_waitcnt vmcnt(4)" ::: "memory");
        else                  asm volatile("s_waitcnt vmcnt(0)" ::: "memory");
        __builtin_amdgcn_s_barrier();

        const char* bufb = smem + (j & 3) * 32768;
        bf16x8 af[8], bfr[4];
#pragma unroll
        for (int mi = 0; mi < 8; mi++) af[mi] = *(const bf16x8*)(bufb + aoff[mi]);
#pragma unroll
        for (int nj = 0; nj < 4; nj++) bfr[nj] = *(const bf16x8*)(bufb + boff[nj]);

        if (j + 3 < nph) STAGE4((j + 3) & 3, (j + 3) * 32);

        __builtin_amdgcn_s_setprio(1);
#pragma unroll
        for (int mi = 0; mi < 8; mi++)
#pragma unroll
            for (int nj = 0; nj < 4; nj++)
                acc[mi][nj] = __builtin_amdgcn_mfma_f32_16x16x32_bf16(af[mi], bfr[nj], acc[mi][nj], 0, 0, 0);
        __builtin_amdgcn_s_setprio(0);
    }
}

#define ACC_INIT() \
    f32x4 acc[8][4]; \
    _Pragma("unroll") for (int i = 0; i < 8; i++) \
    _Pragma("unroll") for (int jj = 0; jj < 4; jj++) acc[i][jj] = (f32x4){0.f, 0.f, 0.f, 0.f};

// x[16384,1024] @ W[z]^T + b -> q (x1/32), k, vt (transposed [B][D][S])
// grid: 768 blocks, chunked XCD swizzle (96 per XCD)
__global__ __launch_bounds__(512, 2) void gemm_qkv(
    const unsigned short* __restrict__ xb, const unsigned short* __restrict__ wb,
    const float* __restrict__ bq, const float* __restrict__ bk, const float* __restrict__ bv,
    unsigned short* __restrict__ qb, unsigned short* __restrict__ kb, unsigned short* __restrict__ vt)
{
    extern __shared__ char smem[];
    const int bid = blockIdx.x;
    const int lb = (bid & 7) * 96 + (bid >> 3);       // bijective (768 % 8 == 0)
    const int bz = lb >> 8;                            // 0..2
    const int r = lb & 255;
    const int m0 = (r >> 2) * 256, n0 = (r & 3) * 256;
    const float* bias = (bz == 0) ? bq : ((bz == 1) ? bk : bv);
    ACC_INIT();
    gemm256_core(xb + (size_t)m0 * DIM, wb + (size_t)bz * DIM * DIM + (size_t)n0 * DIM,
                 DIM, DIM, DIM, smem, acc);
    const int lane = threadIdx.x & 63, wid = threadIdx.x >> 6;
    const int wm = wid >> 2, wn = wid & 3;
    const float scale = (bz == 0) ? 0.03125f : 1.0f;
    unsigned short* C = (bz == 0) ? qb : kb;
#pragma unroll
    for (int mig = 0; mig < 8; mig++)
#pragma unroll
        for (int nj = 0; nj < 4; nj++) {
            int col = n0 + wn * 64 + nj * 16 + (lane & 15);
            float bcol = bias[col];
#pragma unroll
            for (int rr = 0; rr < 4; rr++) {
                int row = m0 + wm * 128 + mig * 16 + (lane >> 4) * 4 + rr;
                float v = (acc[mig][nj][rr] + bcol) * scale;
                if (bz < 2) {
                    C[(size_t)row * DIM + col] = f2bf(v);
                } else {
                    int b = row >> 11, s = row & 2047;
                    vt[((size_t)b << 21) + ((size_t)col << 11) + s] = f2bf(v);
                }
            }
        }
}

// S[b] = q[b] * k[b]^T (q pre-scaled), fp16 out. grid 512, one batch per XCD.
__global__ __launch_bounds__(512, 2) void gemm_qk(
    const unsigned short* __restrict__ qb, const unsigned short* __restrict__ kb,
    unsigned short* __restrict__ sb)
{
    extern __shared__ char smem[];
    const int bid = blockIdx.x;
    const int lb = (bid & 7) * 64 + (bid >> 3);
    const int b = lb >> 6;
    const int r = lb & 63;
    const int m0 = (r >> 3) * 256, n0 = (r & 7) * 256;
    ACC_INIT();
    gemm256_core(qb + ((size_t)b * SEQ + m0) * DIM, kb + ((size_t)b * SEQ + n0) * DIM,
                 DIM, DIM, DIM, smem, acc);
    const int lane = threadIdx.x & 63, wid = threadIdx.x >> 6;
    const int wm = wid >> 2, wn = wid & 3;
    _Float16* sh = (_Float16*)sb + (size_t)b * SEQ * SEQ;
#pragma unroll
    for (int mig = 0; mig < 8; mig++)
#pragma unroll
        for (int nj = 0; nj < 4; nj++) {
            int col = n0 + wn * 64 + nj * 16 + (lane & 15);
#pragma unroll
            for (int rr = 0; rr < 4; rr++) {
                int row = m0 + wm * 128 + mig * 16 + (lane >> 4) * 4 + rr;
                sh[(size_t)row * SEQ + col] = (_Float16)acc[mig][nj][rr];
            }
        }
}

// Row softmax fp16 -> normalized bf16 P in place
__global__ __launch_bounds__(256) void softmax_p(unsigned short* __restrict__ sb)
{
    const int lane = threadIdx.x & 63, wid = threadIdx.x >> 6;
    const size_t row = (size_t)blockIdx.x * 4 + wid;
    unsigned short* rp = sb + row * SEQ;
    float v[32];
#pragma unroll
    for (int j = 0; j < 8; j++) {
        h4 h = *(const h4*)(rp + (j * 64 + lane) * 4);
#pragma unroll
        for (int e = 0; e < 4; e++) v[j * 4 + e] = (float)h[e];
    }
    float m = -1e30f;
#pragma unroll
    for (int i = 0; i < 32; i++) m = fmaxf(m, v[i]);
#pragma unroll
    for (int msk = 1; msk <= 32; msk <<= 1) m = fmaxf(m, __shfl_xor(m, msk, 64));
    float s = 0.f;
#pragma unroll
    for (int i = 0; i < 32; i++) { v[i] = __expf(v[i] - m); s += v[i]; }
#pragma unroll
    for (int msk = 1; msk <= 32; msk <<= 1) s += __shfl_xor(s, msk, 64);
    float inv = 1.0f / s;
#pragma unroll
    for (int j = 0; j < 8; j++) {
        us4 pu = { f2bf(v[j * 4] * inv), f2bf(v[j * 4 + 1] * inv),
                   f2bf(v[j * 4 + 2] * inv), f2bf(v[j * 4 + 3] * inv) };
        *(us4*)(rp + (j * 64 + lane) * 4) = pu;
    }
}

// O[b] = P[b] * VT[b]^T. grid 256, one batch per XCD (VT 4MB fits L2).
__global__ __launch_bounds__(512, 2) void gemm_pv(
    const unsigned short* __restrict__ pb, const unsigned short* __restrict__ vt,
    float* __restrict__ out)
{
    extern __shared__ char smem[];
    const int bid = blockIdx.x;
    const int lb = (bid & 7) * 32 + (bid >> 3);
    const int b = lb >> 5;
    const int r = lb & 31;
    const int m0 = (r >> 2) * 256, n0 = (r & 3) * 256;
    ACC_INIT();
    gemm256_core(pb + ((size_t)b * SEQ + m0) * SEQ, vt + ((size_t)b * DIM + n0) * SEQ,
                 SEQ, SEQ, SEQ, smem, acc);
    const int lane = threadIdx.x & 63, wid = threadIdx.x >> 6;
    const int wm = wid >> 2, wn = wid & 3;
    float* O = out + (size_t)b * SEQ * DIM;
#pragma unroll
    for (int mig = 0; mig < 8; mig++)
#pragma unroll
        for (int nj = 0; nj < 4; nj++) {
            int col = n0 + wn * 64 + nj * 16 + (lane & 15);
#pragma unroll
            for (int rr = 0; rr < 4; rr++) {
                int row = m0 + wm * 128 + mig * 16 + (lane >> 4) * 4 + rr;
                O[(size_t)row * DIM + col] = acc[mig][nj][rr];
            }
        }
}

extern "C" void kernel_launch(void* const* d_in, const int* in_sizes, int n_in,
                              void* d_out, int out_size, void* d_ws, size_t ws_size,
                              hipStream_t stream) {
    const float* x  = (const float*)d_in[0];
    const float* Wq = (const float*)d_in[1];
    const float* bq = (const float*)d_in[2];
    const float* Wk = (const float*)d_in[3];
    const float* bk = (const float*)d_in[4];
    const float* Wv = (const float*)d_in[5];
    const float* bv = (const float*)d_in[6];
    float* out = (float*)d_out;
    char* ws = (char*)d_ws;

    unsigned short* xb = (unsigned short*)(ws);                  // 32 MiB  x bf16
    unsigned short* wb = (unsigned short*)(ws + 33554432);       //  6 MiB  Wq|Wk|Wv bf16
    unsigned short* qb = (unsigned short*)(ws + 39845888);       // 32 MiB  q bf16 (pre-scaled)
    unsigned short* kb = (unsigned short*)(ws + 73400320);       // 32 MiB  k bf16
    unsigned short* vt = (unsigned short*)(ws + 106954752);      // 32 MiB  v^T bf16 [B][D][S]
    unsigned short* sb = (unsigned short*)(ws + 140509184);      // 64 MiB  S fp16 -> P bf16

    cast_f32_bf16<<<dim3(8192), 256, 0, stream>>>(x, xb, 16777216);
    cast_f32_bf16<<<dim3(512), 256, 0, stream>>>(Wq, wb, 1048576);
    cast_f32_bf16<<<dim3(512), 256, 0, stream>>>(Wk, wb + 1048576, 1048576);
    cast_f32_bf16<<<dim3(512), 256, 0, stream>>>(Wv, wb + 2097152, 1048576);

    hipFuncSetAttribute((const void*)gemm_qkv, hipFuncAttributeMaxDynamicSharedMemorySize, 131072);
    hipFuncSetAttribute((const void*)gemm_qk,  hipFuncAttributeMaxDynamicSharedMemorySize, 131072);
    hipFuncSetAttribute((const void*)gemm_pv,  hipFuncAttributeMaxDynamicSharedMemorySize, 131072);

    gemm_qkv<<<dim3(768), 512, 131072, stream>>>(xb, wb, bq, bk, bv, qb, kb, vt);
    gemm_qk<<<dim3(512), 512, 131072, stream>>>(qb, kb, sb);
    softmax_p<<<dim3(4096), 256, 0, stream>>>(sb);
    gemm_pv<<<dim3(256), 512, 131072, stream>>>(sb, vt, out);
}

// Round 5
// 343.947 us; speedup vs baseline: 1.0195x; 1.0195x over previous
//
#include <hip/hip_runtime.h>

#define DIM 1024
#define SEQ 2048

typedef __attribute__((ext_vector_type(8))) short bf16x8;
typedef __attribute__((ext_vector_type(4))) float f32x4;
typedef __attribute__((ext_vector_type(4))) unsigned short us4;
typedef __attribute__((ext_vector_type(4))) _Float16 h4;

__device__ __forceinline__ unsigned short f2bf(float f) {
    union { float f; unsigned int u; } v; v.f = f;
    unsigned int r = (v.u + 0x7FFFu + ((v.u >> 16) & 1u)) >> 16;
    return (unsigned short)r;
}

#define GLOAD(gp, lp) __builtin_amdgcn_global_load_lds( \
    (const __attribute__((address_space(1))) unsigned int*)(gp), \
    (__attribute__((address_space(3))) unsigned int*)(lp), 16, 0, 0)

#define MFMA(a, b, c) __builtin_amdgcn_mfma_f32_16x16x32_bf16((a), (b), (c), 0, 0, 0)

__global__ __launch_bounds__(256) void cast_f32_bf16(const float* __restrict__ src,
                                                     unsigned short* __restrict__ dst, int n) {
    int i = (blockIdx.x * 256 + threadIdx.x) * 8;
    if (i >= n) return;
    float4 a = *(const float4*)(src + i);
    float4 b = *(const float4*)(src + i + 4);
    us4 lo = { f2bf(a.x), f2bf(a.y), f2bf(a.z), f2bf(a.w) };
    us4 hi = { f2bf(b.x), f2bf(b.y), f2bf(b.z), f2bf(b.w) };
    *(us4*)(dst + i) = lo;
    *(us4*)(dst + i + 4) = hi;
}

// ---------------------------------------------------------------------------
// 256x256 GEMM core, m201-style 8-phase schedule. C += A[256,K]*B[256,K]^T.
// 512 thr = 8 waves (2M x 4N), per-wave 128x64. BK=64, 2 dbufs (128 KiB).
// Per K-tile: 4 phases (quadrants), each {ds_read frags || 2 gload staging ->
// barrier -> lgkm0 -> setprio(1) 16 MFMA setprio(0) -> barrier}; vmcnt(4)
// once per tile at phase 3 (never 0 mid-loop).
// LDS per dbuf: A[256][64]swz @0 (32KB), B[256][64]swz @32768. dbuf stride 64KB.
// Swizzle: 16B chunk slot s at row r holds source chunk s ^ (r&7); staging
// pre-swizzles the global source column, reads XOR the chunk index.
// ---------------------------------------------------------------------------
#define STAGE_HALF(G, ld, R0, kt, off) do { \
    GLOAD((G) + (size_t)((R0) + (tid >> 3)) * (ld) + (kt) + csrc,      smem + (off) + tid * 16); \
    GLOAD((G) + (size_t)((R0) + 64 + (tid >> 3)) * (ld) + (kt) + csrc, smem + (off) + 8192 + tid * 16); \
} while (0)

__device__ __forceinline__ void gemm256_core(
    const unsigned short* __restrict__ A, const unsigned short* __restrict__ B,
    int lda, int ldb, int K, char* smem, f32x4 acc[8][4])
{
    const int tid = threadIdx.x;
    const int lane = tid & 63;
    const int wm = (tid >> 6) >> 2;          // 0..1
    const int wn = (tid >> 6) & 3;           // 0..3
    const int csrc = ((tid & 7) ^ ((tid >> 3) & 7)) * 8;   // staging src chunk (elems)
    const int NT = K >> 6;

    const int arow = (wm * 128 + (lane & 15)) * 128;           // A frag row base (bytes)
    const int brow = 32768 + (wn * 64 + (lane & 15)) * 128;    // B frag row base
    const int csw0 = (((lane >> 4) ^ (lane & 7)) * 16);        // ks=0 swizzled chunk
    const int csw1 = (((4 + (lane >> 4)) ^ (lane & 7)) * 16);  // ks=1

    bf16x8 af[8], b01[4], b23[4];

    // prologue: tile0 full, tile1 B-halves
    STAGE_HALF(A, lda, 0,   0, 0);
    STAGE_HALF(A, lda, 128, 0, 16384);
    STAGE_HALF(B, ldb, 0,   0, 32768);
    STAGE_HALF(B, ldb, 128, 0, 49152);
    STAGE_HALF(B, ldb, 0,   64, 65536 + 32768);
    STAGE_HALF(B, ldb, 128, 64, 65536 + 49152);
    asm volatile("s_waitcnt vmcnt(4)" ::: "memory");
    __builtin_amdgcn_s_barrier();

    for (int T = 0; T < NT; ++T) {
        const char* db = smem + (T & 1) * 65536;
        const int d1 = ((T + 1) & 1) * 65536;   // next tile's dbuf (A staging)
        const int d2 = (T & 1) * 65536;         // (T+2)&1 == T&1 (B staging)

        // ---------- phase 0: Q(mi0-3, nj0-1), 12 ds_reads ----------
#pragma unroll
        for (int mi = 0; mi < 4; mi++) {
            af[mi * 2]     = *(const bf16x8*)(db + arow + mi * 2048 + csw0);
            af[mi * 2 + 1] = *(const bf16x8*)(db + arow + mi * 2048 + csw1);
        }
#pragma unroll
        for (int nj = 0; nj < 2; nj++) {
            b01[nj * 2]     = *(const bf16x8*)(db + brow + nj * 2048 + csw0);
            b01[nj * 2 + 1] = *(const bf16x8*)(db + brow + nj * 2048 + csw1);
        }
        if (T + 1 < NT) STAGE_HALF(A, lda, 0, (T + 1) * 64, d1);
        asm volatile("s_waitcnt lgkmcnt(8)" ::: "memory");
        __builtin_amdgcn_s_barrier();
        asm volatile("s_waitcnt lgkmcnt(0)" ::: "memory");
        __builtin_amdgcn_sched_barrier(0);
        __builtin_amdgcn_s_setprio(1);
#pragma unroll
        for (int ks = 0; ks < 2; ks++)
#pragma unroll
            for (int mi = 0; mi < 4; mi++)
#pragma unroll
                for (int nj = 0; nj < 2; nj++)
                    acc[mi][nj] = MFMA(af[mi * 2 + ks], b01[nj * 2 + ks], acc[mi][nj]);
        __builtin_amdgcn_s_setprio(0);
        __builtin_amdgcn_s_barrier();

        // ---------- phase 1: Q(mi0-3, nj2-3), 4 ds_reads ----------
#pragma unroll
        for (int nj = 0; nj < 2; nj++) {
            b23[nj * 2]     = *(const bf16x8*)(db + brow + (nj + 2) * 2048 + csw0);
            b23[nj * 2 + 1] = *(const bf16x8*)(db + brow + (nj + 2) * 2048 + csw1);
        }
        if (T + 1 < NT) STAGE_HALF(A, lda, 128, (T + 1) * 64, d1 + 16384);
        __builtin_amdgcn_s_barrier();
        asm volatile("s_waitcnt lgkmcnt(0)" ::: "memory");
        __builtin_amdgcn_sched_barrier(0);
        __builtin_amdgcn_s_setprio(1);
#pragma unroll
        for (int ks = 0; ks < 2; ks++)
#pragma unroll
            for (int mi = 0; mi < 4; mi++)
#pragma unroll
                for (int nj = 0; nj < 2; nj++)
                    acc[mi][nj + 2] = MFMA(af[mi * 2 + ks], b23[nj * 2 + ks], acc[mi][nj + 2]);
        __builtin_amdgcn_s_setprio(0);
        __builtin_amdgcn_s_barrier();

        // ---------- phase 2: Q(mi4-7, nj0-1), 8 ds_reads ----------
#pragma unroll
        for (int mi = 0; mi < 4; mi++) {
            af[mi * 2]     = *(const bf16x8*)(db + arow + (mi + 4) * 2048 + csw0);
            af[mi * 2 + 1] = *(const bf16x8*)(db + arow + (mi + 4) * 2048 + csw1);
        }
        if (T + 2 < NT) STAGE_HALF(B, ldb, 0, (T + 2) * 64, d2 + 32768);
        __builtin_amdgcn_s_barrier();
        asm volatile("s_waitcnt lgkmcnt(0)" ::: "memory");
        __builtin_amdgcn_sched_barrier(0);
        __builtin_amdgcn_s_setprio(1);
#pragma unroll
        for (int ks = 0; ks < 2; ks++)
#pragma unroll
            for (int mi = 0; mi < 4; mi++)
#pragma unroll
                for (int nj = 0; nj < 2; nj++)
                    acc[mi + 4][nj] = MFMA(af[mi * 2 + ks], b01[nj * 2 + ks], acc[mi + 4][nj]);
        __builtin_amdgcn_s_setprio(0);
        __builtin_amdgcn_s_barrier();

        // ---------- phase 3: Q(mi4-7, nj2-3), 0 ds_reads ----------
        if (T + 2 < NT) STAGE_HALF(B, ldb, 128, (T + 2) * 64, d2 + 49152);
        __builtin_amdgcn_s_barrier();
        __builtin_amdgcn_s_setprio(1);
#pragma unroll
        for (int ks = 0; ks < 2; ks++)
#pragma unroll
            for (int mi = 0; mi < 4; mi++)
#pragma unroll
                for (int nj = 0; nj < 2; nj++)
                    acc[mi + 4][nj + 2] = MFMA(af[mi * 2 + ks], b23[nj * 2 + ks], acc[mi + 4][nj + 2]);
        __builtin_amdgcn_s_setprio(0);
        if (T + 2 < NT) asm volatile("s_waitcnt vmcnt(4)" ::: "memory");
        else            asm volatile("s_waitcnt vmcnt(0)" ::: "memory");
        __builtin_amdgcn_s_barrier();
    }
}

#define ACC_INIT() \
    f32x4 acc[8][4]; \
    _Pragma("unroll") for (int i = 0; i < 8; i++) \
    _Pragma("unroll") for (int jj = 0; jj < 4; jj++) acc[i][jj] = (f32x4){0.f, 0.f, 0.f, 0.f};

// x[16384,1024] @ W[z]^T + b -> q (x1/32), k, vt (transposed [B][D][S])
__global__ __launch_bounds__(512, 2) void gemm_qkv(
    const unsigned short* __restrict__ xb, const unsigned short* __restrict__ wb,
    const float* __restrict__ bq, const float* __restrict__ bk, const float* __restrict__ bv,
    unsigned short* __restrict__ qb, unsigned short* __restrict__ kb, unsigned short* __restrict__ vt)
{
    extern __shared__ char smem[];
    const int bid = blockIdx.x;
    const int lb = (bid & 7) * 96 + (bid >> 3);       // bijective (768 % 8 == 0)
    const int bz = lb >> 8;                            // 0..2
    const int r = lb & 255;
    const int m0 = (r >> 2) * 256, n0 = (r & 3) * 256;
    const float* bias = (bz == 0) ? bq : ((bz == 1) ? bk : bv);
    ACC_INIT();
    gemm256_core(xb + (size_t)m0 * DIM, wb + (size_t)bz * DIM * DIM + (size_t)n0 * DIM,
                 DIM, DIM, DIM, smem, acc);
    const int lane = threadIdx.x & 63, wid = threadIdx.x >> 6;
    const int wm = wid >> 2, wn = wid & 3;
    const float scale = (bz == 0) ? 0.03125f : 1.0f;
    unsigned short* C = (bz == 0) ? qb : kb;
#pragma unroll
    for (int mig = 0; mig < 8; mig++)
#pragma unroll
        for (int nj = 0; nj < 4; nj++) {
            int col = n0 + wn * 64 + nj * 16 + (lane & 15);
            float bcol = bias[col];
#pragma unroll
            for (int rr = 0; rr < 4; rr++) {
                int row = m0 + wm * 128 + mig * 16 + (lane >> 4) * 4 + rr;
                float v = (acc[mig][nj][rr] + bcol) * scale;
                if (bz < 2) {
                    C[(size_t)row * DIM + col] = f2bf(v);
                } else {
                    int b = row >> 11, s = row & 2047;
                    vt[((size_t)b << 21) + ((size_t)col << 11) + s] = f2bf(v);
                }
            }
        }
}

// S[b] = q[b] * k[b]^T (q pre-scaled), fp16 out
__global__ __launch_bounds__(512, 2) void gemm_qk(
    const unsigned short* __restrict__ qb, const unsigned short* __restrict__ kb,
    unsigned short* __restrict__ sb)
{
    extern __shared__ char smem[];
    const int bid = blockIdx.x;
    const int lb = (bid & 7) * 64 + (bid >> 3);
    const int b = lb >> 6;
    const int r = lb & 63;
    const int m0 = (r >> 3) * 256, n0 = (r & 7) * 256;
    ACC_INIT();
    gemm256_core(qb + ((size_t)b * SEQ + m0) * DIM, kb + ((size_t)b * SEQ + n0) * DIM,
                 DIM, DIM, DIM, smem, acc);
    const int lane = threadIdx.x & 63, wid = threadIdx.x >> 6;
    const int wm = wid >> 2, wn = wid & 3;
    _Float16* sh = (_Float16*)sb + (size_t)b * SEQ * SEQ;
#pragma unroll
    for (int mig = 0; mig < 8; mig++)
#pragma unroll
        for (int nj = 0; nj < 4; nj++) {
            int col = n0 + wn * 64 + nj * 16 + (lane & 15);
#pragma unroll
            for (int rr = 0; rr < 4; rr++) {
                int row = m0 + wm * 128 + mig * 16 + (lane >> 4) * 4 + rr;
                sh[(size_t)row * SEQ + col] = (_Float16)acc[mig][nj][rr];
            }
        }
}

// Row softmax fp16 -> normalized bf16 P in place
__global__ __launch_bounds__(256) void softmax_p(unsigned short* __restrict__ sb)
{
    const int lane = threadIdx.x & 63, wid = threadIdx.x >> 6;
    const size_t row = (size_t)blockIdx.x * 4 + wid;
    unsigned short* rp = sb + row * SEQ;
    float v[32];
#pragma unroll
    for (int j = 0; j < 8; j++) {
        h4 h = *(const h4*)(rp + (j * 64 + lane) * 4);
#pragma unroll
        for (int e = 0; e < 4; e++) v[j * 4 + e] = (float)h[e];
    }
    float m = -1e30f;
#pragma unroll
    for (int i = 0; i < 32; i++) m = fmaxf(m, v[i]);
#pragma unroll
    for (int msk = 1; msk <= 32; msk <<= 1) m = fmaxf(m, __shfl_xor(m, msk, 64));
    float s = 0.f;
#pragma unroll
    for (int i = 0; i < 32; i++) { v[i] = __expf(v[i] - m); s += v[i]; }
#pragma unroll
    for (int msk = 1; msk <= 32; msk <<= 1) s += __shfl_xor(s, msk, 64);
    float inv = 1.0f / s;
#pragma unroll
    for (int j = 0; j < 8; j++) {
        us4 pu = { f2bf(v[j * 4] * inv), f2bf(v[j * 4 + 1] * inv),
                   f2bf(v[j * 4 + 2] * inv), f2bf(v[j * 4 + 3] * inv) };
        *(us4*)(rp + (j * 64 + lane) * 4) = pu;
    }
}

// O[b] = P[b] * VT[b]^T
__global__ __launch_bounds__(512, 2) void gemm_pv(
    const unsigned short* __restrict__ pb, const unsigned short* __restrict__ vt,
    float* __restrict__ out)
{
    extern __shared__ char smem[];
    const int bid = blockIdx.x;
    const int lb = (bid & 7) * 32 + (bid >> 3);
    const int b = lb >> 5;
    const int r = lb & 31;
    const int m0 = (r >> 2) * 256, n0 = (r & 3) * 256;
    ACC_INIT();
    gemm256_core(pb + ((size_t)b * SEQ + m0) * SEQ, vt + ((size_t)b * DIM + n0) * SEQ,
                 SEQ, SEQ, SEQ, smem, acc);
    const int lane = threadIdx.x & 63, wid = threadIdx.x >> 6;
    const int wm = wid >> 2, wn = wid & 3;
    float* O = out + (size_t)b * SEQ * DIM;
#pragma unroll
    for (int mig = 0; mig < 8; mig++)
#pragma unroll
        for (int nj = 0; nj < 4; nj++) {
            int col = n0 + wn * 64 + nj * 16 + (lane & 15);
#pragma unroll
            for (int rr = 0; rr < 4; rr++) {
                int row = m0 + wm * 128 + mig * 16 + (lane >> 4) * 4 + rr;
                O[(size_t)row * DIM + col] = acc[mig][nj][rr];
            }
        }
}

extern "C" void kernel_launch(void* const* d_in, const int* in_sizes, int n_in,
                              void* d_out, int out_size, void* d_ws, size_t ws_size,
                              hipStream_t stream) {
    const float* x  = (const float*)d_in[0];
    const float* Wq = (const float*)d_in[1];
    const float* bq = (const float*)d_in[2];
    const float* Wk = (const float*)d_in[3];
    const float* bk = (const float*)d_in[4];
    const float* Wv = (const float*)d_in[5];
    const float* bv = (const float*)d_in[6];
    float* out = (float*)d_out;
    char* ws = (char*)d_ws;

    unsigned short* xb = (unsigned short*)(ws);                  // 32 MiB  x bf16
    unsigned short* wb = (unsigned short*)(ws + 33554432);       //  6 MiB  Wq|Wk|Wv bf16
    unsigned short* qb = (unsigned short*)(ws + 39845888);       // 32 MiB  q bf16 (pre-scaled)
    unsigned short* kb = (unsigned short*)(ws + 73400320);       // 32 MiB  k bf16
    unsigned short* vt = (unsigned short*)(ws + 106954752);      // 32 MiB  v^T bf16 [B][D][S]
    unsigned short* sb = (unsigned short*)(ws + 140509184);      // 64 MiB  S fp16 -> P bf16

    cast_f32_bf16<<<dim3(8192), 256, 0, stream>>>(x, xb, 16777216);
    cast_f32_bf16<<<dim3(512), 256, 0, stream>>>(Wq, wb, 1048576);
    cast_f32_bf16<<<dim3(512), 256, 0, stream>>>(Wk, wb + 1048576, 1048576);
    cast_f32_bf16<<<dim3(512), 256, 0, stream>>>(Wv, wb + 2097152, 1048576);

    hipFuncSetAttribute((const void*)gemm_qkv, hipFuncAttributeMaxDynamicSharedMemorySize, 131072);
    hipFuncSetAttribute((const void*)gemm_qk,  hipFuncAttributeMaxDynamicSharedMemorySize, 131072);
    hipFuncSetAttribute((const void*)gemm_pv,  hipFuncAttributeMaxDynamicSharedMemorySize, 131072);

    gemm_qkv<<<dim3(768), 512, 131072, stream>>>(xb, wb, bq, bk, bv, qb, kb, vt);
    gemm_qk<<<dim3(512), 512, 131072, stream>>>(qb, kb, sb);
    softmax_p<<<dim3(4096), 256, 0, stream>>>(sb);
    gemm_pv<<<dim3(256), 512, 131072, stream>>>(sb, vt, out);
}

// Round 6
// 336.891 us; speedup vs baseline: 1.0408x; 1.0209x over previous
//
#include <hip/hip_runtime.h>

#define DIM 1024
#define SEQ 2048

typedef __attribute__((ext_vector_type(8))) short bf16x8;
typedef __attribute__((ext_vector_type(16))) float f32x16;
typedef __attribute__((ext_vector_type(4))) unsigned short us4;
typedef __attribute__((ext_vector_type(4))) _Float16 h4;

__device__ __forceinline__ unsigned short f2bf(float f) {
    union { float f; unsigned int u; } v; v.f = f;
    unsigned int r = (v.u + 0x7FFFu + ((v.u >> 16) & 1u)) >> 16;
    return (unsigned short)r;
}

#define GLOAD(gp, lp) __builtin_amdgcn_global_load_lds( \
    (const __attribute__((address_space(1))) unsigned int*)(gp), \
    (__attribute__((address_space(3))) unsigned int*)(lp), 16, 0, 0)

#define MFMA32(a, b, c) __builtin_amdgcn_mfma_f32_32x32x16_bf16((a), (b), (c), 0, 0, 0)

__global__ __launch_bounds__(256) void cast_f32_bf16(const float* __restrict__ src,
                                                     unsigned short* __restrict__ dst, int n) {
    int i = (blockIdx.x * 256 + threadIdx.x) * 8;
    if (i >= n) return;
    float4 a = *(const float4*)(src + i);
    float4 b = *(const float4*)(src + i + 4);
    us4 lo = { f2bf(a.x), f2bf(a.y), f2bf(a.z), f2bf(a.w) };
    us4 hi = { f2bf(b.x), f2bf(b.y), f2bf(b.z), f2bf(b.w) };
    *(us4*)(dst + i) = lo;
    *(us4*)(dst + i + 4) = hi;
}

// ---------------------------------------------------------------------------
// 256x256 GEMM core on 32x32x16 MFMA. C += A[256,K]*B[256,K]^T (row-major K).
// 512 thr = 8 waves (2M x 4N), per-wave 128x64 = 4x2 frags of 32x32 (f32x16).
// BK=32, 4 LDS bufs of 32 KiB (A[256][32] @0, B[256][32] @16K), swizzle:
// 16B slot s of row r holds source chunk s ^ (r&3), even bank spread for both
// the 32-row fragment reads and the linear staging writes. Per tile: 1 barrier,
// 4 gload (stage T+2), 12 ds_read_b128, 16 MFMA under setprio. vmcnt(4)
// counted at head (never 0 mid-loop).
// ---------------------------------------------------------------------------
__device__ __forceinline__ void gemm256_core(
    const unsigned short* __restrict__ A, const unsigned short* __restrict__ B,
    int lda, int ldb, int K, char* smem, f32x16 acc[4][2])
{
    const int tid = threadIdx.x;
    const int lane = tid & 63;
    const int wm = (tid >> 6) >> 2;          // 0..1
    const int wn = (tid >> 6) & 3;           // 0..3
    const int l31 = lane & 31, lhi = lane >> 5;

    // staging: thread t -> row t>>2 of each 128-row half, slot t&3 holds
    // source chunk (t&3)^(row&3)
    const int srow = tid >> 2;
    const int schunk = ((tid & 3) ^ (srow & 3)) * 8;
    const unsigned short* pa0 = A + (size_t)srow * lda + schunk;
    const unsigned short* pa1 = A + (size_t)(128 + srow) * lda + schunk;
    const unsigned short* pb0 = B + (size_t)srow * ldb + schunk;
    const unsigned short* pb1 = B + (size_t)(128 + srow) * ldb + schunk;
    const int doff = tid * 16;

    const int abase = (wm * 128 + l31) * 64;             // A frag row base (bytes)
    const int bbase = 16384 + (wn * 64 + l31) * 64;      // B frag row base
    const int csw0 = (lhi ^ (l31 & 3)) * 16;             // ks=0 swizzled slot
    const int csw1 = ((2 + lhi) ^ (l31 & 3)) * 16;       // ks=1

    const int NT = K >> 5;

#define STAGE32(bufi, kt) do { \
    char* d = smem + (bufi) * 32768 + doff; \
    GLOAD(pa0 + (kt), d); \
    GLOAD(pa1 + (kt), d + 8192); \
    GLOAD(pb0 + (kt), d + 16384); \
    GLOAD(pb1 + (kt), d + 24576); \
} while (0)

    STAGE32(0, 0);
    STAGE32(1, 32);

    for (int T = 0; T < NT; ++T) {
        if (T + 1 < NT) asm volatile("s_waitcnt vmcnt(4)" ::: "memory");
        else            asm volatile("s_waitcnt vmcnt(0)" ::: "memory");
        __builtin_amdgcn_s_barrier();

        if (T + 2 < NT) STAGE32((T + 2) & 3, (T + 2) * 32);

        const char* db = smem + (T & 3) * 32768;
        bf16x8 a0[4], a1[4], b0[2], b1[2];
#pragma unroll
        for (int mi = 0; mi < 4; mi++) {
            a0[mi] = *(const bf16x8*)(db + abase + mi * 2048 + csw0);
            a1[mi] = *(const bf16x8*)(db + abase + mi * 2048 + csw1);
        }
#pragma unroll
        for (int nj = 0; nj < 2; nj++) {
            b0[nj] = *(const bf16x8*)(db + bbase + nj * 2048 + csw0);
            b1[nj] = *(const bf16x8*)(db + bbase + nj * 2048 + csw1);
        }

        __builtin_amdgcn_s_setprio(1);
#pragma unroll
        for (int mi = 0; mi < 4; mi++)
#pragma unroll
            for (int nj = 0; nj < 2; nj++)
                acc[mi][nj] = MFMA32(a0[mi], b0[nj], acc[mi][nj]);
#pragma unroll
        for (int mi = 0; mi < 4; mi++)
#pragma unroll
            for (int nj = 0; nj < 2; nj++)
                acc[mi][nj] = MFMA32(a1[mi], b1[nj], acc[mi][nj]);
        __builtin_amdgcn_s_setprio(0);
    }
#undef STAGE32
}

#define ACC_INIT() \
    f32x16 acc[4][2]; \
    _Pragma("unroll") for (int i = 0; i < 4; i++) \
    _Pragma("unroll") for (int jj = 0; jj < 2; jj++) acc[i][jj] = (f32x16){}; \

// C/D layout (32x32): row = (r&3) + 8*(r>>2) + 4*(lane>>5), col = lane&31.

// BZ=0: q = (xW^T + b)/32, bf16 row-major. BZ=1: k, bf16 row-major.
// BZ=2: v -> vt transposed [B][D][S] bf16.
template<int BZ>
__global__ __launch_bounds__(512, 2) void gemm_qkv_t(
    const unsigned short* __restrict__ xb, const unsigned short* __restrict__ w,
    const float* __restrict__ bias, unsigned short* __restrict__ C)
{
    extern __shared__ char smem[];
    const int bid = blockIdx.x;
    const int lb = (bid & 7) * 32 + (bid >> 3);   // 256 blocks, XCD-chunked
    const int m0 = (lb >> 2) * 256, n0 = (lb & 3) * 256;
    ACC_INIT();
    gemm256_core(xb + (size_t)m0 * DIM, w + (size_t)n0 * DIM, DIM, DIM, DIM, smem, acc);
    const int lane = threadIdx.x & 63, wid = threadIdx.x >> 6;
    const int wm = wid >> 2, wn = wid & 3;
    const int l31 = lane & 31, lhi = lane >> 5;
    const float scale = (BZ == 0) ? 0.03125f : 1.0f;
#pragma unroll
    for (int mi = 0; mi < 4; mi++)
#pragma unroll
        for (int nj = 0; nj < 2; nj++) {
            const int col = n0 + wn * 64 + nj * 32 + l31;
            const float bcol = bias[col];
#pragma unroll
            for (int r = 0; r < 16; r++) {
                const int row = m0 + wm * 128 + mi * 32 + (r & 3) + 8 * (r >> 2) + 4 * lhi;
                const float v = (acc[mi][nj][r] + bcol) * scale;
                if (BZ < 2) {
                    C[(size_t)row * DIM + col] = f2bf(v);
                } else {
                    const int b = row >> 11, s = row & 2047;
                    C[((size_t)b << 21) + ((size_t)col << 11) + s] = f2bf(v);
                }
            }
        }
}

// S[b] = q[b] * k[b]^T (q pre-scaled), fp16 out [B][S][S]
__global__ __launch_bounds__(512, 2) void gemm_qk(
    const unsigned short* __restrict__ qb, const unsigned short* __restrict__ kb,
    unsigned short* __restrict__ sb)
{
    extern __shared__ char smem[];
    const int bid = blockIdx.x;
    const int lb = (bid & 7) * 64 + (bid >> 3);
    const int b = lb >> 6;
    const int r0 = lb & 63;
    const int m0 = (r0 >> 3) * 256, n0 = (r0 & 7) * 256;
    ACC_INIT();
    gemm256_core(qb + ((size_t)b * SEQ + m0) * DIM, kb + ((size_t)b * SEQ + n0) * DIM,
                 DIM, DIM, DIM, smem, acc);
    const int lane = threadIdx.x & 63, wid = threadIdx.x >> 6;
    const int wm = wid >> 2, wn = wid & 3;
    const int l31 = lane & 31, lhi = lane >> 5;
    _Float16* sh = (_Float16*)sb + (size_t)b * SEQ * SEQ;
#pragma unroll
    for (int mi = 0; mi < 4; mi++)
#pragma unroll
        for (int nj = 0; nj < 2; nj++) {
            const int col = n0 + wn * 64 + nj * 32 + l31;
#pragma unroll
            for (int r = 0; r < 16; r++) {
                const int row = m0 + wm * 128 + mi * 32 + (r & 3) + 8 * (r >> 2) + 4 * lhi;
                sh[(size_t)row * SEQ + col] = (_Float16)acc[mi][nj][r];
            }
        }
}

// Row softmax fp16 -> normalized bf16 P in place
__global__ __launch_bounds__(256) void softmax_p(unsigned short* __restrict__ sb)
{
    const int lane = threadIdx.x & 63, wid = threadIdx.x >> 6;
    const size_t row = (size_t)blockIdx.x * 4 + wid;
    unsigned short* rp = sb + row * SEQ;
    float v[32];
#pragma unroll
    for (int j = 0; j < 8; j++) {
        h4 h = *(const h4*)(rp + (j * 64 + lane) * 4);
#pragma unroll
        for (int e = 0; e < 4; e++) v[j * 4 + e] = (float)h[e];
    }
    float m = -1e30f;
#pragma unroll
    for (int i = 0; i < 32; i++) m = fmaxf(m, v[i]);
#pragma unroll
    for (int msk = 1; msk <= 32; msk <<= 1) m = fmaxf(m, __shfl_xor(m, msk, 64));
    float s = 0.f;
#pragma unroll
    for (int i = 0; i < 32; i++) { v[i] = __expf(v[i] - m); s += v[i]; }
#pragma unroll
    for (int msk = 1; msk <= 32; msk <<= 1) s += __shfl_xor(s, msk, 64);
    float inv = 1.0f / s;
#pragma unroll
    for (int j = 0; j < 8; j++) {
        us4 pu = { f2bf(v[j * 4] * inv), f2bf(v[j * 4 + 1] * inv),
                   f2bf(v[j * 4 + 2] * inv), f2bf(v[j * 4 + 3] * inv) };
        *(us4*)(rp + (j * 64 + lane) * 4) = pu;
    }
}

// O[b] = P[b] * VT[b]^T, f32 out
__global__ __launch_bounds__(512, 2) void gemm_pv(
    const unsigned short* __restrict__ pb, const unsigned short* __restrict__ vt,
    float* __restrict__ out)
{
    extern __shared__ char smem[];
    const int bid = blockIdx.x;
    const int lb = (bid & 7) * 32 + (bid >> 3);
    const int b = lb >> 5;
    const int r0 = lb & 31;
    const int m0 = (r0 >> 2) * 256, n0 = (r0 & 3) * 256;
    ACC_INIT();
    gemm256_core(pb + ((size_t)b * SEQ + m0) * SEQ, vt + ((size_t)b * DIM + n0) * SEQ,
                 SEQ, SEQ, SEQ, smem, acc);
    const int lane = threadIdx.x & 63, wid = threadIdx.x >> 6;
    const int wm = wid >> 2, wn = wid & 3;
    const int l31 = lane & 31, lhi = lane >> 5;
    float* O = out + (size_t)b * SEQ * DIM;
#pragma unroll
    for (int mi = 0; mi < 4; mi++)
#pragma unroll
        for (int nj = 0; nj < 2; nj++) {
            const int col = n0 + wn * 64 + nj * 32 + l31;
#pragma unroll
            for (int r = 0; r < 16; r++) {
                const int row = m0 + wm * 128 + mi * 32 + (r & 3) + 8 * (r >> 2) + 4 * lhi;
                O[(size_t)row * DIM + col] = acc[mi][nj][r];
            }
        }
}

extern "C" void kernel_launch(void* const* d_in, const int* in_sizes, int n_in,
                              void* d_out, int out_size, void* d_ws, size_t ws_size,
                              hipStream_t stream) {
    const float* x  = (const float*)d_in[0];
    const float* Wq = (const float*)d_in[1];
    const float* bq = (const float*)d_in[2];
    const float* Wk = (const float*)d_in[3];
    const float* bk = (const float*)d_in[4];
    const float* Wv = (const float*)d_in[5];
    const float* bv = (const float*)d_in[6];
    float* out = (float*)d_out;
    char* ws = (char*)d_ws;

    unsigned short* xb = (unsigned short*)(ws);                  // 32 MiB  x bf16
    unsigned short* wb = (unsigned short*)(ws + 33554432);       //  6 MiB  Wq|Wk|Wv bf16
    unsigned short* qb = (unsigned short*)(ws + 39845888);       // 32 MiB  q bf16 (pre-scaled)
    unsigned short* kb = (unsigned short*)(ws + 73400320);       // 32 MiB  k bf16
    unsigned short* vt = (unsigned short*)(ws + 106954752);      // 32 MiB  v^T bf16 [B][D][S]
    unsigned short* sb = (unsigned short*)(ws + 140509184);      // 64 MiB  S fp16 -> P bf16

    cast_f32_bf16<<<dim3(8192), 256, 0, stream>>>(x, xb, 16777216);
    cast_f32_bf16<<<dim3(512), 256, 0, stream>>>(Wq, wb, 1048576);
    cast_f32_bf16<<<dim3(512), 256, 0, stream>>>(Wk, wb + 1048576, 1048576);
    cast_f32_bf16<<<dim3(512), 256, 0, stream>>>(Wv, wb + 2097152, 1048576);

    hipFuncSetAttribute((const void*)gemm_qkv_t<0>, hipFuncAttributeMaxDynamicSharedMemorySize, 131072);
    hipFuncSetAttribute((const void*)gemm_qkv_t<1>, hipFuncAttributeMaxDynamicSharedMemorySize, 131072);
    hipFuncSetAttribute((const void*)gemm_qkv_t<2>, hipFuncAttributeMaxDynamicSharedMemorySize, 131072);
    hipFuncSetAttribute((const void*)gemm_qk,  hipFuncAttributeMaxDynamicSharedMemorySize, 131072);
    hipFuncSetAttribute((const void*)gemm_pv,  hipFuncAttributeMaxDynamicSharedMemorySize, 131072);

    gemm_qkv_t<0><<<dim3(256), 512, 131072, stream>>>(xb, wb,           bq, qb);
    gemm_qkv_t<1><<<dim3(256), 512, 131072, stream>>>(xb, wb + 1048576, bk, kb);
    gemm_qkv_t<2><<<dim3(256), 512, 131072, stream>>>(xb, wb + 2097152, bv, vt);
    gemm_qk<<<dim3(512), 512, 131072, stream>>>(qb, kb, sb);
    softmax_p<<<dim3(4096), 256, 0, stream>>>(sb);
    gemm_pv<<<dim3(256), 512, 131072, stream>>>(sb, vt, out);
}

// Round 7
// 307.931 us; speedup vs baseline: 1.1387x; 1.0940x over previous
//
#include <hip/hip_runtime.h>

#define DIM 1024
#define SEQ 2048

typedef __attribute__((ext_vector_type(8))) short bf16x8;
typedef __attribute__((ext_vector_type(16))) float f32x16;
typedef __attribute__((ext_vector_type(4))) unsigned short us4;
typedef __attribute__((ext_vector_type(4))) _Float16 h4;

__device__ __forceinline__ unsigned short f2bf(float f) {
    union { float f; unsigned int u; } v; v.f = f;
    unsigned int r = (v.u + 0x7FFFu + ((v.u >> 16) & 1u)) >> 16;
    return (unsigned short)r;
}

#define GLOAD(gp, lp) __builtin_amdgcn_global_load_lds( \
    (const __attribute__((address_space(1))) unsigned int*)(gp), \
    (__attribute__((address_space(3))) unsigned int*)(lp), 16, 0, 0)

#define MFMA32(a, b, c) __builtin_amdgcn_mfma_f32_32x32x16_bf16((a), (b), (c), 0, 0, 0)

__global__ __launch_bounds__(256) void cast_f32_bf16(const float* __restrict__ src,
                                                     unsigned short* __restrict__ dst, int n) {
    int i = (blockIdx.x * 256 + threadIdx.x) * 8;
    if (i >= n) return;
    float4 a = *(const float4*)(src + i);
    float4 b = *(const float4*)(src + i + 4);
    us4 lo = { f2bf(a.x), f2bf(a.y), f2bf(a.z), f2bf(a.w) };
    us4 hi = { f2bf(b.x), f2bf(b.y), f2bf(b.z), f2bf(b.w) };
    *(us4*)(dst + i) = lo;
    *(us4*)(dst + i + 4) = hi;
}

// ---------------------------------------------------------------------------
// 256x256 GEMM core on 32x32x16 MFMA. C += A[256,K]*B[256,K]^T (row-major K).
// 512 thr = 8 waves (2M x 4N), per-wave 128x64 = 4x2 frags of 32x32 (f32x16).
// BK=32, 4 LDS bufs of 32 KiB. Swizzle: 16B slot s of row r holds source
// chunk s ^ ((r>>1)&3). Bank check: position p=(r&1)*4 + slot covers all 8
// 16B-positions once per 8 consecutive lanes for A-frag reads (row=lane&31,
// slot=lhi^f), both k-halves, and B-frag reads (base multiple of 32) ->
// conflict-free; staging writes linear. Per tile: 1 barrier, 4 gload (stage
// T+2), 12 ds_read_b128, 16 MFMA under setprio, counted vmcnt(4).
// ---------------------------------------------------------------------------
__device__ __forceinline__ void gemm256_core(
    const unsigned short* __restrict__ A, const unsigned short* __restrict__ B,
    int lda, int ldb, int K, char* smem, f32x16 acc[4][2])
{
    const int tid = threadIdx.x;
    const int lane = tid & 63;
    const int wm = (tid >> 6) >> 2;          // 0..1
    const int wn = (tid >> 6) & 3;           // 0..3
    const int l31 = lane & 31, lhi = lane >> 5;

    // staging: thread t -> row t>>2, slot t&3 holds source chunk (t&3)^((row>>1)&3)
    const int srow = tid >> 2;
    const int schunk = ((tid & 3) ^ ((tid >> 3) & 3)) * 8;
    const unsigned short* pa0 = A + (size_t)srow * lda + schunk;
    const unsigned short* pa1 = A + (size_t)(128 + srow) * lda + schunk;
    const unsigned short* pb0 = B + (size_t)srow * ldb + schunk;
    const unsigned short* pb1 = B + (size_t)(128 + srow) * ldb + schunk;
    const int doff = tid * 16;

    const int abase = (wm * 128 + l31) * 64;             // A frag row base (bytes)
    const int bbase = 16384 + (wn * 64 + l31) * 64;      // B frag row base
    const int fsw = (l31 >> 1) & 3;                      // row swizzle key
    const int csw0 = (lhi ^ fsw) * 16;                   // ks=0 slot
    const int csw1 = ((2 + lhi) ^ fsw) * 16;             // ks=1 slot

    const int NT = K >> 5;

#define STAGE32(bufi, kt) do { \
    char* d = smem + (bufi) * 32768 + doff; \
    GLOAD(pa0 + (kt), d); \
    GLOAD(pa1 + (kt), d + 8192); \
    GLOAD(pb0 + (kt), d + 16384); \
    GLOAD(pb1 + (kt), d + 24576); \
} while (0)

    STAGE32(0, 0);
    STAGE32(1, 32);

    for (int T = 0; T < NT; ++T) {
        if (T + 1 < NT) asm volatile("s_waitcnt vmcnt(4)" ::: "memory");
        else            asm volatile("s_waitcnt vmcnt(0)" ::: "memory");
        __builtin_amdgcn_s_barrier();

        if (T + 2 < NT) STAGE32((T + 2) & 3, (T + 2) * 32);

        const char* db = smem + (T & 3) * 32768;
        bf16x8 a0[4], a1[4], b0[2], b1[2];
#pragma unroll
        for (int mi = 0; mi < 4; mi++) {
            a0[mi] = *(const bf16x8*)(db + abase + mi * 2048 + csw0);
            a1[mi] = *(const bf16x8*)(db + abase + mi * 2048 + csw1);
        }
#pragma unroll
        for (int nj = 0; nj < 2; nj++) {
            b0[nj] = *(const bf16x8*)(db + bbase + nj * 2048 + csw0);
            b1[nj] = *(const bf16x8*)(db + bbase + nj * 2048 + csw1);
        }

        __builtin_amdgcn_s_setprio(1);
#pragma unroll
        for (int mi = 0; mi < 4; mi++)
#pragma unroll
            for (int nj = 0; nj < 2; nj++)
                acc[mi][nj] = MFMA32(a0[mi], b0[nj], acc[mi][nj]);
#pragma unroll
        for (int mi = 0; mi < 4; mi++)
#pragma unroll
            for (int nj = 0; nj < 2; nj++)
                acc[mi][nj] = MFMA32(a1[mi], b1[nj], acc[mi][nj]);
        __builtin_amdgcn_s_setprio(0);
    }
#undef STAGE32
}

#define ACC_INIT() \
    f32x16 acc[4][2]; \
    _Pragma("unroll") for (int i = 0; i < 4; i++) \
    _Pragma("unroll") for (int jj = 0; jj < 2; jj++) acc[i][jj] = (f32x16){}; \

// C/D layout (32x32): row = (r&3) + 8*(r>>2) + 4*(lane>>5), col = lane&31.

// BZ=0: q = (xW^T + b)/32, bf16 row-major. BZ=1: k, bf16 row-major.
// BZ=2: v -> vt transposed [B][D][S] bf16 (us4-packed stores).
template<int BZ>
__global__ __launch_bounds__(512, 2) void gemm_qkv_t(
    const unsigned short* __restrict__ xb, const unsigned short* __restrict__ w,
    const float* __restrict__ bias, unsigned short* __restrict__ C)
{
    extern __shared__ char smem[];
    const int bid = blockIdx.x;
    const int lb = (bid & 7) * 32 + (bid >> 3);   // 256 blocks, XCD-chunked
    const int m0 = (lb >> 2) * 256, n0 = (lb & 3) * 256;
    ACC_INIT();
    gemm256_core(xb + (size_t)m0 * DIM, w + (size_t)n0 * DIM, DIM, DIM, DIM, smem, acc);
    const int lane = threadIdx.x & 63, wid = threadIdx.x >> 6;
    const int wm = wid >> 2, wn = wid & 3;
    const int l31 = lane & 31, lhi = lane >> 5;
    const float scale = (BZ == 0) ? 0.03125f : 1.0f;
#pragma unroll
    for (int mi = 0; mi < 4; mi++)
#pragma unroll
        for (int nj = 0; nj < 2; nj++) {
            const int col = n0 + wn * 64 + nj * 32 + l31;
            const float bcol = bias[col];
            if (BZ < 2) {
#pragma unroll
                for (int r = 0; r < 16; r++) {
                    const int row = m0 + wm * 128 + mi * 32 + (r & 3) + 8 * (r >> 2) + 4 * lhi;
                    C[(size_t)row * DIM + col] = f2bf((acc[mi][nj][r] + bcol) * scale);
                }
            } else {
#pragma unroll
                for (int r4 = 0; r4 < 4; r4++) {
                    const int s0 = m0 + wm * 128 + mi * 32 + 8 * r4 + 4 * lhi;
                    const int b = s0 >> 11, s = s0 & 2047;
                    us4 pk = { f2bf(acc[mi][nj][r4 * 4] + bcol),
                               f2bf(acc[mi][nj][r4 * 4 + 1] + bcol),
                               f2bf(acc[mi][nj][r4 * 4 + 2] + bcol),
                               f2bf(acc[mi][nj][r4 * 4 + 3] + bcol) };
                    *(us4*)&C[((size_t)b << 21) + ((size_t)col << 11) + s] = pk;
                }
            }
        }
}

// S[b] = q[b] * k[b]^T (q pre-scaled), fp16 out [B][S][S]
__global__ __launch_bounds__(512, 2) void gemm_qk(
    const unsigned short* __restrict__ qb, const unsigned short* __restrict__ kb,
    unsigned short* __restrict__ sb)
{
    extern __shared__ char smem[];
    const int bid = blockIdx.x;
    const int lb = (bid & 7) * 64 + (bid >> 3);
    const int b = lb >> 6;
    const int r0 = lb & 63;
    const int m0 = (r0 >> 3) * 256, n0 = (r0 & 7) * 256;
    ACC_INIT();
    gemm256_core(qb + ((size_t)b * SEQ + m0) * DIM, kb + ((size_t)b * SEQ + n0) * DIM,
                 DIM, DIM, DIM, smem, acc);
    const int lane = threadIdx.x & 63, wid = threadIdx.x >> 6;
    const int wm = wid >> 2, wn = wid & 3;
    const int l31 = lane & 31, lhi = lane >> 5;
    _Float16* sh = (_Float16*)sb + (size_t)b * SEQ * SEQ;
#pragma unroll
    for (int mi = 0; mi < 4; mi++)
#pragma unroll
        for (int nj = 0; nj < 2; nj++) {
            const int col = n0 + wn * 64 + nj * 32 + l31;
#pragma unroll
            for (int r = 0; r < 16; r++) {
                const int row = m0 + wm * 128 + mi * 32 + (r & 3) + 8 * (r >> 2) + 4 * lhi;
                sh[(size_t)row * SEQ + col] = (_Float16)acc[mi][nj][r];
            }
        }
}

// Row softmax fp16 -> normalized bf16 P in place
__global__ __launch_bounds__(256) void softmax_p(unsigned short* __restrict__ sb)
{
    const int lane = threadIdx.x & 63, wid = threadIdx.x >> 6;
    const size_t row = (size_t)blockIdx.x * 4 + wid;
    unsigned short* rp = sb + row * SEQ;
    float v[32];
#pragma unroll
    for (int j = 0; j < 8; j++) {
        h4 h = *(const h4*)(rp + (j * 64 + lane) * 4);
#pragma unroll
        for (int e = 0; e < 4; e++) v[j * 4 + e] = (float)h[e];
    }
    float m = -1e30f;
#pragma unroll
    for (int i = 0; i < 32; i++) m = fmaxf(m, v[i]);
#pragma unroll
    for (int msk = 1; msk <= 32; msk <<= 1) m = fmaxf(m, __shfl_xor(m, msk, 64));
    float s = 0.f;
#pragma unroll
    for (int i = 0; i < 32; i++) { v[i] = __expf(v[i] - m); s += v[i]; }
#pragma unroll
    for (int msk = 1; msk <= 32; msk <<= 1) s += __shfl_xor(s, msk, 64);
    float inv = 1.0f / s;
#pragma unroll
    for (int j = 0; j < 8; j++) {
        us4 pu = { f2bf(v[j * 4] * inv), f2bf(v[j * 4 + 1] * inv),
                   f2bf(v[j * 4 + 2] * inv), f2bf(v[j * 4 + 3] * inv) };
        *(us4*)(rp + (j * 64 + lane) * 4) = pu;
    }
}

// O[b] = P[b] * VT[b]^T, f32 out
__global__ __launch_bounds__(512, 2) void gemm_pv(
    const unsigned short* __restrict__ pb, const unsigned short* __restrict__ vt,
    float* __restrict__ out)
{
    extern __shared__ char smem[];
    const int bid = blockIdx.x;
    const int lb = (bid & 7) * 32 + (bid >> 3);
    const int b = lb >> 5;
    const int r0 = lb & 31;
    const int m0 = (r0 >> 2) * 256, n0 = (r0 & 3) * 256;
    ACC_INIT();
    gemm256_core(pb + ((size_t)b * SEQ + m0) * SEQ, vt + ((size_t)b * DIM + n0) * SEQ,
                 SEQ, SEQ, SEQ, smem, acc);
    const int lane = threadIdx.x & 63, wid = threadIdx.x >> 6;
    const int wm = wid >> 2, wn = wid & 3;
    const int l31 = lane & 31, lhi = lane >> 5;
    float* O = out + (size_t)b * SEQ * DIM;
#pragma unroll
    for (int mi = 0; mi < 4; mi++)
#pragma unroll
        for (int nj = 0; nj < 2; nj++) {
            const int col = n0 + wn * 64 + nj * 32 + l31;
#pragma unroll
            for (int r = 0; r < 16; r++) {
                const int row = m0 + wm * 128 + mi * 32 + (r & 3) + 8 * (r >> 2) + 4 * lhi;
                O[(size_t)row * DIM + col] = acc[mi][nj][r];
            }
        }
}

extern "C" void kernel_launch(void* const* d_in, const int* in_sizes, int n_in,
                              void* d_out, int out_size, void* d_ws, size_t ws_size,
                              hipStream_t stream) {
    const float* x  = (const float*)d_in[0];
    const float* Wq = (const float*)d_in[1];
    const float* bq = (const float*)d_in[2];
    const float* Wk = (const float*)d_in[3];
    const float* bk = (const float*)d_in[4];
    const float* Wv = (const float*)d_in[5];
    const float* bv = (const float*)d_in[6];
    float* out = (float*)d_out;
    char* ws = (char*)d_ws;

    unsigned short* xb = (unsigned short*)(ws);                  // 32 MiB  x bf16
    unsigned short* wb = (unsigned short*)(ws + 33554432);       //  6 MiB  Wq|Wk|Wv bf16
    unsigned short* qb = (unsigned short*)(ws + 39845888);       // 32 MiB  q bf16 (pre-scaled)
    unsigned short* kb = (unsigned short*)(ws + 73400320);       // 32 MiB  k bf16
    unsigned short* vt = (unsigned short*)(ws + 106954752);      // 32 MiB  v^T bf16 [B][D][S]
    unsigned short* sb = (unsigned short*)(ws + 140509184);      // 64 MiB  S fp16 -> P bf16

    cast_f32_bf16<<<dim3(8192), 256, 0, stream>>>(x, xb, 16777216);
    cast_f32_bf16<<<dim3(512), 256, 0, stream>>>(Wq, wb, 1048576);
    cast_f32_bf16<<<dim3(512), 256, 0, stream>>>(Wk, wb + 1048576, 1048576);
    cast_f32_bf16<<<dim3(512), 256, 0, stream>>>(Wv, wb + 2097152, 1048576);

    hipFuncSetAttribute((const void*)gemm_qkv_t<0>, hipFuncAttributeMaxDynamicSharedMemorySize, 131072);
    hipFuncSetAttribute((const void*)gemm_qkv_t<1>, hipFuncAttributeMaxDynamicSharedMemorySize, 131072);
    hipFuncSetAttribute((const void*)gemm_qkv_t<2>, hipFuncAttributeMaxDynamicSharedMemorySize, 131072);
    hipFuncSetAttribute((const void*)gemm_qk,  hipFuncAttributeMaxDynamicSharedMemorySize, 131072);
    hipFuncSetAttribute((const void*)gemm_pv,  hipFuncAttributeMaxDynamicSharedMemorySize, 131072);

    gemm_qkv_t<0><<<dim3(256), 512, 131072, stream>>>(xb, wb,           bq, qb);
    gemm_qkv_t<1><<<dim3(256), 512, 131072, stream>>>(xb, wb + 1048576, bk, kb);
    gemm_qkv_t<2><<<dim3(256), 512, 131072, stream>>>(xb, wb + 2097152, bv, vt);
    gemm_qk<<<dim3(512), 512, 131072, stream>>>(qb, kb, sb);
    softmax_p<<<dim3(4096), 256, 0, stream>>>(sb);
    gemm_pv<<<dim3(256), 512, 131072, stream>>>(sb, vt, out);
}

// Round 8
// 286.794 us; speedup vs baseline: 1.2226x; 1.0737x over previous
//
#include <hip/hip_runtime.h>

#define DIM 1024
#define SEQ 2048

typedef __attribute__((ext_vector_type(8))) short bf16x8;
typedef __attribute__((ext_vector_type(16))) float f32x16;
typedef __attribute__((ext_vector_type(4))) unsigned short us4;
typedef __attribute__((ext_vector_type(4))) _Float16 h4;

__device__ __forceinline__ unsigned short f2bf(float f) {
    union { float f; unsigned int u; } v; v.f = f;
    unsigned int r = (v.u + 0x7FFFu + ((v.u >> 16) & 1u)) >> 16;
    return (unsigned short)r;
}

#define GLOAD(gp, lp) __builtin_amdgcn_global_load_lds( \
    (const __attribute__((address_space(1))) unsigned int*)(gp), \
    (__attribute__((address_space(3))) unsigned int*)(lp), 16, 0, 0)

#define MFMA32(a, b, c) __builtin_amdgcn_mfma_f32_32x32x16_bf16((a), (b), (c), 0, 0, 0)

__global__ __launch_bounds__(256) void cast_f32_bf16(const float* __restrict__ src,
                                                     unsigned short* __restrict__ dst, int n) {
    int i = (blockIdx.x * 256 + threadIdx.x) * 8;
    if (i >= n) return;
    float4 a = *(const float4*)(src + i);
    float4 b = *(const float4*)(src + i + 4);
    us4 lo = { f2bf(a.x), f2bf(a.y), f2bf(a.z), f2bf(a.w) };
    us4 hi = { f2bf(b.x), f2bf(b.y), f2bf(b.z), f2bf(b.w) };
    *(us4*)(dst + i) = lo;
    *(us4*)(dst + i + 4) = hi;
}

// ---------------------------------------------------------------------------
// 256x256 GEMM core, 32x32x16 MFMA, BK=64, 128B LDS rows, 8-slot XOR swizzle
// (slot s of row r holds source chunk s^(r&7) -- the R5-verified 0-conflict
// pattern: bank_start = 4*slot covers all 8 slots per 8 consecutive lanes).
// 512 thr = 8 waves (2M x 4N), per-wave 128x64 = 4x2 frags. 2 dbufs of 64 KiB
// (A[256][64] @0, B[256][64] @32768), 1 block/CU. Per K64 tile: vmcnt(0) +
// barrier, then two ks-halves each {12 ds_read_b128 || 4 gload staging ->
// 16 MFMA under setprio}.
// ---------------------------------------------------------------------------
__device__ __forceinline__ void gemm256_core(
    const unsigned short* __restrict__ A, const unsigned short* __restrict__ B,
    int lda, int ldb, int K, char* smem, f32x16 acc[4][2])
{
    const int tid = threadIdx.x;
    const int lane = tid & 63;
    const int wm = (tid >> 6) >> 2;          // 0..1
    const int wn = (tid >> 6) & 3;           // 0..3
    const int l31 = lane & 31, lhi = lane >> 5;

    // staging: thread t covers row (t>>3)+64h, slot t&7 holds chunk (t&7)^(row&7)
    const int schunk = ((tid & 7) ^ ((tid >> 3) & 7)) * 8;
    const unsigned short* paw = A + (size_t)(tid >> 3) * lda + schunk;
    const unsigned short* pbw = B + (size_t)(tid >> 3) * ldb + schunk;
    const int doff = tid * 16;

    const int key = l31 & 7;
    const int abase = (wm * 128 + l31) * 128;            // + mi*4096
    const int bbase = 32768 + (wn * 64 + l31) * 128;     // + nj*4096
    int csw[4];
#pragma unroll
    for (int ks = 0; ks < 4; ks++) csw[ks] = (((ks << 1) | lhi) ^ key) * 16;

    const int NT = K >> 6;

#define STAGE_A(bb, kt) do { \
    GLOAD(paw + (kt),                       smem + (bb) + doff); \
    GLOAD(paw + (kt) + (size_t)64  * lda,   smem + (bb) + 8192 + doff); \
    GLOAD(paw + (kt) + (size_t)128 * lda,   smem + (bb) + 16384 + doff); \
    GLOAD(paw + (kt) + (size_t)192 * lda,   smem + (bb) + 24576 + doff); \
} while (0)
#define STAGE_B(bb, kt) do { \
    GLOAD(pbw + (kt),                       smem + (bb) + 32768 + doff); \
    GLOAD(pbw + (kt) + (size_t)64  * ldb,   smem + (bb) + 40960 + doff); \
    GLOAD(pbw + (kt) + (size_t)128 * ldb,   smem + (bb) + 49152 + doff); \
    GLOAD(pbw + (kt) + (size_t)192 * ldb,   smem + (bb) + 57344 + doff); \
} while (0)

    STAGE_A(0, 0);
    STAGE_B(0, 0);

    for (int T = 0; T < NT; ++T) {
        asm volatile("s_waitcnt vmcnt(0)" ::: "memory");
        __builtin_amdgcn_s_barrier();
        const char* db = smem + (T & 1) * 65536;
        const int nb = ((T + 1) & 1) * 65536;
        bf16x8 a0[4], a1[4], b0[2], b1[2];

        // ---- ks half 0 (k 0..31) ----
#pragma unroll
        for (int mi = 0; mi < 4; mi++) {
            a0[mi] = *(const bf16x8*)(db + abase + mi * 4096 + csw[0]);
            a1[mi] = *(const bf16x8*)(db + abase + mi * 4096 + csw[1]);
        }
#pragma unroll
        for (int nj = 0; nj < 2; nj++) {
            b0[nj] = *(const bf16x8*)(db + bbase + nj * 4096 + csw[0]);
            b1[nj] = *(const bf16x8*)(db + bbase + nj * 4096 + csw[1]);
        }
        if (T + 1 < NT) STAGE_A(nb, (size_t)(T + 1) * 64);
        __builtin_amdgcn_s_setprio(1);
#pragma unroll
        for (int mi = 0; mi < 4; mi++)
#pragma unroll
            for (int nj = 0; nj < 2; nj++)
                acc[mi][nj] = MFMA32(a0[mi], b0[nj], acc[mi][nj]);
#pragma unroll
        for (int mi = 0; mi < 4; mi++)
#pragma unroll
            for (int nj = 0; nj < 2; nj++)
                acc[mi][nj] = MFMA32(a1[mi], b1[nj], acc[mi][nj]);
        __builtin_amdgcn_s_setprio(0);

        // ---- ks half 1 (k 32..63) ----
#pragma unroll
        for (int mi = 0; mi < 4; mi++) {
            a0[mi] = *(const bf16x8*)(db + abase + mi * 4096 + csw[2]);
            a1[mi] = *(const bf16x8*)(db + abase + mi * 4096 + csw[3]);
        }
#pragma unroll
        for (int nj = 0; nj < 2; nj++) {
            b0[nj] = *(const bf16x8*)(db + bbase + nj * 4096 + csw[2]);
            b1[nj] = *(const bf16x8*)(db + bbase + nj * 4096 + csw[3]);
        }
        if (T + 1 < NT) STAGE_B(nb, (size_t)(T + 1) * 64);
        __builtin_amdgcn_s_setprio(1);
#pragma unroll
        for (int mi = 0; mi < 4; mi++)
#pragma unroll
            for (int nj = 0; nj < 2; nj++)
                acc[mi][nj] = MFMA32(a0[mi], b0[nj], acc[mi][nj]);
#pragma unroll
        for (int mi = 0; mi < 4; mi++)
#pragma unroll
            for (int nj = 0; nj < 2; nj++)
                acc[mi][nj] = MFMA32(a1[mi], b1[nj], acc[mi][nj]);
        __builtin_amdgcn_s_setprio(0);
    }
#undef STAGE_A
#undef STAGE_B
}

#define ACC_INIT() \
    f32x16 acc[4][2]; \
    _Pragma("unroll") for (int i = 0; i < 4; i++) \
    _Pragma("unroll") for (int jj = 0; jj < 2; jj++) acc[i][jj] = (f32x16){}; \

// C/D layout (32x32): row = (r&3) + 8*(r>>2) + 4*(lane>>5), col = lane&31.

// BZ=0: q = (xW^T + b)/32, bf16. BZ=1: k, bf16. BZ=2: v -> vt [B][D][S] bf16.
template<int BZ>
__global__ __launch_bounds__(512, 2) void gemm_qkv_t(
    const unsigned short* __restrict__ xb, const unsigned short* __restrict__ w,
    const float* __restrict__ bias, unsigned short* __restrict__ C)
{
    extern __shared__ char smem[];
    const int bid = blockIdx.x;
    const int lb = (bid & 7) * 32 + (bid >> 3);   // 256 blocks, XCD-chunked
    const int m0 = (lb >> 2) * 256, n0 = (lb & 3) * 256;
    ACC_INIT();
    gemm256_core(xb + (size_t)m0 * DIM, w + (size_t)n0 * DIM, DIM, DIM, DIM, smem, acc);
    const int lane = threadIdx.x & 63, wid = threadIdx.x >> 6;
    const int wm = wid >> 2, wn = wid & 3;
    const int l31 = lane & 31, lhi = lane >> 5;
    const float scale = (BZ == 0) ? 0.03125f : 1.0f;
#pragma unroll
    for (int mi = 0; mi < 4; mi++)
#pragma unroll
        for (int nj = 0; nj < 2; nj++) {
            const int col = n0 + wn * 64 + nj * 32 + l31;
            const float bcol = bias[col];
            if (BZ < 2) {
#pragma unroll
                for (int r = 0; r < 16; r++) {
                    const int row = m0 + wm * 128 + mi * 32 + (r & 3) + 8 * (r >> 2) + 4 * lhi;
                    C[(size_t)row * DIM + col] = f2bf((acc[mi][nj][r] + bcol) * scale);
                }
            } else {
#pragma unroll
                for (int r4 = 0; r4 < 4; r4++) {
                    const int s0 = m0 + wm * 128 + mi * 32 + 8 * r4 + 4 * lhi;
                    const int b = s0 >> 11, s = s0 & 2047;
                    us4 pk = { f2bf(acc[mi][nj][r4 * 4] + bcol),
                               f2bf(acc[mi][nj][r4 * 4 + 1] + bcol),
                               f2bf(acc[mi][nj][r4 * 4 + 2] + bcol),
                               f2bf(acc[mi][nj][r4 * 4 + 3] + bcol) };
                    *(us4*)&C[((size_t)b << 21) + ((size_t)col << 11) + s] = pk;
                }
            }
        }
}

// S[b] = q[b] * k[b]^T (q pre-scaled), fp16 out [B][S][S]
__global__ __launch_bounds__(512, 2) void gemm_qk(
    const unsigned short* __restrict__ qb, const unsigned short* __restrict__ kb,
    unsigned short* __restrict__ sb)
{
    extern __shared__ char smem[];
    const int bid = blockIdx.x;
    const int lb = (bid & 7) * 64 + (bid >> 3);
    const int b = lb >> 6;
    const int r0 = lb & 63;
    const int m0 = (r0 >> 3) * 256, n0 = (r0 & 7) * 256;
    ACC_INIT();
    gemm256_core(qb + ((size_t)b * SEQ + m0) * DIM, kb + ((size_t)b * SEQ + n0) * DIM,
                 DIM, DIM, DIM, smem, acc);
    const int lane = threadIdx.x & 63, wid = threadIdx.x >> 6;
    const int wm = wid >> 2, wn = wid & 3;
    const int l31 = lane & 31, lhi = lane >> 5;
    _Float16* sh = (_Float16*)sb + (size_t)b * SEQ * SEQ;
#pragma unroll
    for (int mi = 0; mi < 4; mi++)
#pragma unroll
        for (int nj = 0; nj < 2; nj++) {
            const int col = n0 + wn * 64 + nj * 32 + l31;
#pragma unroll
            for (int r = 0; r < 16; r++) {
                const int row = m0 + wm * 128 + mi * 32 + (r & 3) + 8 * (r >> 2) + 4 * lhi;
                sh[(size_t)row * SEQ + col] = (_Float16)acc[mi][nj][r];
            }
        }
}

// Row softmax fp16 -> normalized bf16 P in place
__global__ __launch_bounds__(256) void softmax_p(unsigned short* __restrict__ sb)
{
    const int lane = threadIdx.x & 63, wid = threadIdx.x >> 6;
    const size_t row = (size_t)blockIdx.x * 4 + wid;
    unsigned short* rp = sb + row * SEQ;
    float v[32];
#pragma unroll
    for (int j = 0; j < 8; j++) {
        h4 h = *(const h4*)(rp + (j * 64 + lane) * 4);
#pragma unroll
        for (int e = 0; e < 4; e++) v[j * 4 + e] = (float)h[e];
    }
    float m = -1e30f;
#pragma unroll
    for (int i = 0; i < 32; i++) m = fmaxf(m, v[i]);
#pragma unroll
    for (int msk = 1; msk <= 32; msk <<= 1) m = fmaxf(m, __shfl_xor(m, msk, 64));
    float s = 0.f;
#pragma unroll
    for (int i = 0; i < 32; i++) { v[i] = __expf(v[i] - m); s += v[i]; }
#pragma unroll
    for (int msk = 1; msk <= 32; msk <<= 1) s += __shfl_xor(s, msk, 64);
    float inv = 1.0f / s;
#pragma unroll
    for (int j = 0; j < 8; j++) {
        us4 pu = { f2bf(v[j * 4] * inv), f2bf(v[j * 4 + 1] * inv),
                   f2bf(v[j * 4 + 2] * inv), f2bf(v[j * 4 + 3] * inv) };
        *(us4*)(rp + (j * 64 + lane) * 4) = pu;
    }
}

// O[b] = P[b] * VT[b]^T, f32 out
__global__ __launch_bounds__(512, 2) void gemm_pv(
    const unsigned short* __restrict__ pb, const unsigned short* __restrict__ vt,
    float* __restrict__ out)
{
    extern __shared__ char smem[];
    const int bid = blockIdx.x;
    const int lb = (bid & 7) * 32 + (bid >> 3);
    const int b = lb >> 5;
    const int r0 = lb & 31;
    const int m0 = (r0 >> 2) * 256, n0 = (r0 & 3) * 256;
    ACC_INIT();
    gemm256_core(pb + ((size_t)b * SEQ + m0) * SEQ, vt + ((size_t)b * DIM + n0) * SEQ,
                 SEQ, SEQ, SEQ, smem, acc);
    const int lane = threadIdx.x & 63, wid = threadIdx.x >> 6;
    const int wm = wid >> 2, wn = wid & 3;
    const int l31 = lane & 31, lhi = lane >> 5;
    float* O = out + (size_t)b * SEQ * DIM;
#pragma unroll
    for (int mi = 0; mi < 4; mi++)
#pragma unroll
        for (int nj = 0; nj < 2; nj++) {
            const int col = n0 + wn * 64 + nj * 32 + l31;
#pragma unroll
            for (int r = 0; r < 16; r++) {
                const int row = m0 + wm * 128 + mi * 32 + (r & 3) + 8 * (r >> 2) + 4 * lhi;
                O[(size_t)row * DIM + col] = acc[mi][nj][r];
            }
        }
}

extern "C" void kernel_launch(void* const* d_in, const int* in_sizes, int n_in,
                              void* d_out, int out_size, void* d_ws, size_t ws_size,
                              hipStream_t stream) {
    const float* x  = (const float*)d_in[0];
    const float* Wq = (const float*)d_in[1];
    const float* bq = (const float*)d_in[2];
    const float* Wk = (const float*)d_in[3];
    const float* bk = (const float*)d_in[4];
    const float* Wv = (const float*)d_in[5];
    const float* bv = (const float*)d_in[6];
    float* out = (float*)d_out;
    char* ws = (char*)d_ws;

    unsigned short* xb = (unsigned short*)(ws);                  // 32 MiB  x bf16
    unsigned short* wb = (unsigned short*)(ws + 33554432);       //  6 MiB  Wq|Wk|Wv bf16
    unsigned short* qb = (unsigned short*)(ws + 39845888);       // 32 MiB  q bf16 (pre-scaled)
    unsigned short* kb = (unsigned short*)(ws + 73400320);       // 32 MiB  k bf16
    unsigned short* vt = (unsigned short*)(ws + 106954752);      // 32 MiB  v^T bf16 [B][D][S]
    unsigned short* sb = (unsigned short*)(ws + 140509184);      // 64 MiB  S fp16 -> P bf16

    cast_f32_bf16<<<dim3(8192), 256, 0, stream>>>(x, xb, 16777216);
    cast_f32_bf16<<<dim3(512), 256, 0, stream>>>(Wq, wb, 1048576);
    cast_f32_bf16<<<dim3(512), 256, 0, stream>>>(Wk, wb + 1048576, 1048576);
    cast_f32_bf16<<<dim3(512), 256, 0, stream>>>(Wv, wb + 2097152, 1048576);

    hipFuncSetAttribute((const void*)gemm_qkv_t<0>, hipFuncAttributeMaxDynamicSharedMemorySize, 131072);
    hipFuncSetAttribute((const void*)gemm_qkv_t<1>, hipFuncAttributeMaxDynamicSharedMemorySize, 131072);
    hipFuncSetAttribute((const void*)gemm_qkv_t<2>, hipFuncAttributeMaxDynamicSharedMemorySize, 131072);
    hipFuncSetAttribute((const void*)gemm_qk,  hipFuncAttributeMaxDynamicSharedMemorySize, 131072);
    hipFuncSetAttribute((const void*)gemm_pv,  hipFuncAttributeMaxDynamicSharedMemorySize, 131072);

    gemm_qkv_t<0><<<dim3(256), 512, 131072, stream>>>(xb, wb,           bq, qb);
    gemm_qkv_t<1><<<dim3(256), 512, 131072, stream>>>(xb, wb + 1048576, bk, kb);
    gemm_qkv_t<2><<<dim3(256), 512, 131072, stream>>>(xb, wb + 2097152, bv, vt);
    gemm_qk<<<dim3(512), 512, 131072, stream>>>(qb, kb, sb);
    softmax_p<<<dim3(4096), 256, 0, stream>>>(sb);
    gemm_pv<<<dim3(256), 512, 131072, stream>>>(sb, vt, out);
}